// Round 1
// baseline (898.888 us; speedup 1.0000x reference)
//
#include <hip/hip_runtime.h>
#include <cstdint>
#include <cstddef>

#define BN_EPS 1e-5f

static inline size_t align_up(size_t v, size_t a) { return (v + a - 1) & ~(a - 1); }

// ---------------- CSR build ----------------

__global__ void hist_kernel(const int* __restrict__ dst, int* __restrict__ counts, int E) {
    int i = blockIdx.x * 256 + threadIdx.x;
    if (i < E) atomicAdd(&counts[dst[i]], 1);
}

// 2048 elements per block, 256 threads x 8 items
__global__ void scan1_kernel(const int* __restrict__ counts, int* __restrict__ bsums, int n) {
    int tid  = threadIdx.x;
    int base = blockIdx.x * 2048 + tid * 8;
    int s = 0;
#pragma unroll
    for (int j = 0; j < 8; ++j) { int idx = base + j; if (idx < n) s += counts[idx]; }
#pragma unroll
    for (int off = 32; off > 0; off >>= 1) s += __shfl_down(s, off);
    __shared__ int wtot[4];
    if ((tid & 63) == 0) wtot[tid >> 6] = s;
    __syncthreads();
    if (tid == 0) bsums[blockIdx.x] = wtot[0] + wtot[1] + wtot[2] + wtot[3];
}

__global__ void scan2_kernel(int* bsums, int nblk) {
    if (threadIdx.x == 0 && blockIdx.x == 0) {
        int run = 0;
        for (int i = 0; i < nblk; ++i) { int v = bsums[i]; bsums[i] = run; run += v; }
    }
}

__global__ void scan3_kernel(const int* __restrict__ counts, const int* __restrict__ bsums,
                             int* __restrict__ rowp, int n, int Etot) {
    int tid  = threadIdx.x;
    int base = blockIdx.x * 2048 + tid * 8;
    int loc[8]; int s = 0;
#pragma unroll
    for (int j = 0; j < 8; ++j) { loc[j] = s; int idx = base + j; if (idx < n) s += counts[idx]; }
    int lane = tid & 63, wid = tid >> 6;
    int inc = s;
#pragma unroll
    for (int off = 1; off < 64; off <<= 1) { int t = __shfl_up(inc, off); if (lane >= off) inc += t; }
    __shared__ int wtot[4];
    if (lane == 63) wtot[wid] = inc;
    __syncthreads();
    int woff = 0;
    for (int w = 0; w < wid; ++w) woff += wtot[w];
    int texc = woff + inc - s;   // exclusive offset of this thread within block
    int bo = bsums[blockIdx.x];
#pragma unroll
    for (int j = 0; j < 8; ++j) { int idx = base + j; if (idx < n) rowp[idx] = bo + texc + loc[j]; }
    if (tid == 0 && blockIdx.x == 0) rowp[n] = Etot;
}

__global__ void fill_kernel(const int* __restrict__ src, const int* __restrict__ dst,
                            int* __restrict__ cursor, int* __restrict__ col, int E) {
    int i = blockIdx.x * 256 + threadIdx.x;
    if (i < E) {
        int d = dst[i];
        int pos = atomicAdd(&cursor[d], 1);
        col[pos] = src[i];
    }
}

// ---------------- Fused dual GEMM: Y = X@Wl^T, Z = X@Wr^T + bias ----------------
// X: [n,128] fp32, Wl/Wr: [FOUT,128], block handles 64 nodes, 256 threads.

template <int FOUT>
__global__ __launch_bounds__(256) void gemm_dual_kernel(
    const float* __restrict__ X, const float* __restrict__ Wl,
    const float* __restrict__ Wr, const float* __restrict__ bz,
    float* __restrict__ Y, float* __restrict__ Z, int n)
{
    constexpr int FPT = FOUT / 32;   // feats per thread (4 or 2)
    constexpr int KC  = 32;
    constexpr int XS  = 68;          // 64 + 4 pad (bank-conflict break, keeps 16B align)
    constexpr int WS  = FOUT + 4;
    __shared__ __align__(16) float xs[KC][XS];
    __shared__ __align__(16) float wls[KC][WS];
    __shared__ __align__(16) float wrs[KC][WS];

    const int tid = threadIdx.x;
    const int tx  = tid & 31;
    const int ty  = tid >> 5;
    const int n0  = blockIdx.x * 64;

    float accY[8][FPT], accZ[8][FPT];
#pragma unroll
    for (int i = 0; i < 8; ++i)
#pragma unroll
        for (int j = 0; j < FPT; ++j) { accY[i][j] = 0.f; accZ[i][j] = 0.f; }

    for (int k0 = 0; k0 < 128; k0 += KC) {
        // stage X tile transposed: xs[k][node]
#pragma unroll
        for (int t = tid; t < 64 * KC / 4; t += 256) {
            int nl = t >> 3;
            int kk = (t & 7) * 4;
            int gn = n0 + nl;
            float4 v = make_float4(0.f, 0.f, 0.f, 0.f);
            if (gn < n) v = *(const float4*)&X[(size_t)gn * 128 + k0 + kk];
            xs[kk + 0][nl] = v.x; xs[kk + 1][nl] = v.y;
            xs[kk + 2][nl] = v.z; xs[kk + 3][nl] = v.w;
        }
        // stage W tiles transposed: wls[k][feat]
#pragma unroll
        for (int t = tid; t < FOUT * KC / 4; t += 256) {
            int j  = t >> 3;
            int kk = (t & 7) * 4;
            float4 a = *(const float4*)&Wl[j * 128 + k0 + kk];
            wls[kk + 0][j] = a.x; wls[kk + 1][j] = a.y;
            wls[kk + 2][j] = a.z; wls[kk + 3][j] = a.w;
            float4 b = *(const float4*)&Wr[j * 128 + k0 + kk];
            wrs[kk + 0][j] = b.x; wrs[kk + 1][j] = b.y;
            wrs[kk + 2][j] = b.z; wrs[kk + 3][j] = b.w;
        }
        __syncthreads();
#pragma unroll
        for (int k = 0; k < KC; ++k) {
            float xv[8];
            {
                float4 xa = *(const float4*)&xs[k][ty * 8];
                float4 xb = *(const float4*)&xs[k][ty * 8 + 4];
                xv[0] = xa.x; xv[1] = xa.y; xv[2] = xa.z; xv[3] = xa.w;
                xv[4] = xb.x; xv[5] = xb.y; xv[6] = xb.z; xv[7] = xb.w;
            }
            float wlv[FPT], wrv[FPT];
            if constexpr (FPT == 4) {
                float4 wa = *(const float4*)&wls[k][tx * 4];
                float4 wb = *(const float4*)&wrs[k][tx * 4];
                wlv[0] = wa.x; wlv[1] = wa.y; wlv[2] = wa.z; wlv[3] = wa.w;
                wrv[0] = wb.x; wrv[1] = wb.y; wrv[2] = wb.z; wrv[3] = wb.w;
            } else {
                float2 wa = *(const float2*)&wls[k][tx * 2];
                float2 wb = *(const float2*)&wrs[k][tx * 2];
                wlv[0] = wa.x; wlv[1] = wa.y;
                wrv[0] = wb.x; wrv[1] = wb.y;
            }
#pragma unroll
            for (int i = 0; i < 8; ++i)
#pragma unroll
                for (int j = 0; j < FPT; ++j) {
                    accY[i][j] = fmaf(xv[i], wlv[j], accY[i][j]);
                    accZ[i][j] = fmaf(xv[i], wrv[j], accZ[i][j]);
                }
        }
        __syncthreads();
    }

    float bv[FPT];
#pragma unroll
    for (int j = 0; j < FPT; ++j) bv[j] = bz[tx * FPT + j];
#pragma unroll
    for (int i = 0; i < 8; ++i) {
        int gn = n0 + ty * 8 + i;
        if (gn < n) {
            if constexpr (FPT == 4) {
                *(float4*)&Y[(size_t)gn * FOUT + tx * 4] =
                    make_float4(accY[i][0], accY[i][1], accY[i][2], accY[i][3]);
                *(float4*)&Z[(size_t)gn * FOUT + tx * 4] =
                    make_float4(accZ[i][0] + bv[0], accZ[i][1] + bv[1],
                                accZ[i][2] + bv[2], accZ[i][3] + bv[3]);
            } else {
                *(float2*)&Y[(size_t)gn * FOUT + tx * 2] = make_float2(accY[i][0], accY[i][1]);
                *(float2*)&Z[(size_t)gn * FOUT + tx * 2] =
                    make_float2(accZ[i][0] + bv[0], accZ[i][1] + bv[1]);
            }
        }
    }
}

// ---------------- CSR aggregation: one wave per node ----------------
// H layer: h = relu( (agg/deg + z - rm) * g/sqrt(rv+eps) + b ), in-place on Z buffer.

__global__ __launch_bounds__(256) void agg_bn_relu_kernel(
    const float* __restrict__ Y1, const int* __restrict__ col,
    const int* __restrict__ rowp, float* __restrict__ H,
    const float* __restrict__ g, const float* __restrict__ b,
    const float* __restrict__ rm, const float* __restrict__ rv, int n)
{
    int node = blockIdx.x * 4 + (threadIdx.x >> 6);
    int lane = threadIdx.x & 63;
    if (node >= n) return;
    int beg = rowp[node], end = rowp[node + 1];
    float s0x = 0.f, s0y = 0.f, s1x = 0.f, s1y = 0.f;
    float s2x = 0.f, s2y = 0.f, s3x = 0.f, s3y = 0.f;
    int e = beg;
    for (; e + 4 <= end; e += 4) {
        int c0 = col[e], c1 = col[e + 1], c2 = col[e + 2], c3 = col[e + 3];
        float2 v0 = *(const float2*)&Y1[(size_t)c0 * 128 + lane * 2];
        float2 v1 = *(const float2*)&Y1[(size_t)c1 * 128 + lane * 2];
        float2 v2 = *(const float2*)&Y1[(size_t)c2 * 128 + lane * 2];
        float2 v3 = *(const float2*)&Y1[(size_t)c3 * 128 + lane * 2];
        s0x += v0.x; s0y += v0.y; s1x += v1.x; s1y += v1.y;
        s2x += v2.x; s2y += v2.y; s3x += v3.x; s3y += v3.y;
    }
    for (; e < end; ++e) {
        int c0 = col[e];
        float2 v0 = *(const float2*)&Y1[(size_t)c0 * 128 + lane * 2];
        s0x += v0.x; s0y += v0.y;
    }
    float sx = (s0x + s1x) + (s2x + s3x);
    float sy = (s0y + s1y) + (s2y + s3y);
    int d = end - beg;
    float inv = 1.0f / (float)(d > 1 ? d : 1);
    float2 z  = *(const float2*)&H[(size_t)node * 128 + lane * 2];
    float2 gg = *(const float2*)&g[lane * 2];
    float2 bb = *(const float2*)&b[lane * 2];
    float2 mm = *(const float2*)&rm[lane * 2];
    float2 vv = *(const float2*)&rv[lane * 2];
    float sc0 = gg.x * rsqrtf(vv.x + BN_EPS);
    float sc1 = gg.y * rsqrtf(vv.y + BN_EPS);
    float h0 = (sx * inv + z.x - mm.x) * sc0 + bb.x;
    float h1 = (sy * inv + z.y - mm.y) * sc1 + bb.y;
    float2 outv;
    outv.x = fmaxf(h0, 0.f);
    outv.y = fmaxf(h1, 0.f);
    *(float2*)&H[(size_t)node * 128 + lane * 2] = outv;
}

// out[node] += (sum_{e} Y2[col[e]]) / deg    (out already holds h@Wr2^T + bl2)
__global__ __launch_bounds__(256) void agg_out_kernel(
    const float* __restrict__ Y2, const int* __restrict__ col,
    const int* __restrict__ rowp, float* __restrict__ out, int n)
{
    int node = blockIdx.x * 4 + (threadIdx.x >> 6);
    int lane = threadIdx.x & 63;
    if (node >= n) return;
    int beg = rowp[node], end = rowp[node + 1];
    float a0 = 0.f, a1 = 0.f, a2 = 0.f, a3 = 0.f;
    int e = beg;
    for (; e + 4 <= end; e += 4) {
        int c0 = col[e], c1 = col[e + 1], c2 = col[e + 2], c3 = col[e + 3];
        a0 += Y2[(size_t)c0 * 64 + lane];
        a1 += Y2[(size_t)c1 * 64 + lane];
        a2 += Y2[(size_t)c2 * 64 + lane];
        a3 += Y2[(size_t)c3 * 64 + lane];
    }
    for (; e < end; ++e) a0 += Y2[(size_t)col[e] * 64 + lane];
    float s = (a0 + a1) + (a2 + a3);
    int d = end - beg;
    float inv = 1.0f / (float)(d > 1 ? d : 1);
    out[(size_t)node * 64 + lane] += s * inv;
}

// ---------------- launch ----------------

extern "C" void kernel_launch(void* const* d_in, const int* in_sizes, int n_in,
                              void* d_out, int out_size, void* d_ws, size_t ws_size,
                              hipStream_t stream)
{
    const float* x     = (const float*)d_in[0];
    const int*   ei    = (const int*)d_in[1];
    const float* Wl1   = (const float*)d_in[2];
    const float* bl1   = (const float*)d_in[3];
    const float* Wr1   = (const float*)d_in[4];
    const float* Wl2   = (const float*)d_in[5];
    const float* bl2   = (const float*)d_in[6];
    const float* Wr2   = (const float*)d_in[7];
    const float* bn_g  = (const float*)d_in[8];
    const float* bn_b  = (const float*)d_in[9];
    const float* bn_rm = (const float*)d_in[10];
    const float* bn_rv = (const float*)d_in[11];

    const int N = in_sizes[0] / 128;
    const int E = in_sizes[1] / 2;
    const int* src = ei;
    const int* dst = ei + E;

    char* ws = (char*)d_ws;
    size_t off = 0;
    auto alloc = [&](size_t bytes) { size_t o = off; off = align_up(off + bytes, 256); return (void*)(ws + o); };
    int*   counts = (int*)alloc((size_t)N * 4);
    int*   rowp   = (int*)alloc((size_t)(N + 1) * 4);
    int*   cursor = (int*)alloc((size_t)N * 4);
    int*   bsums  = (int*)alloc(4096);
    int*   col    = (int*)alloc((size_t)E * 4);
    float* y1     = (float*)alloc((size_t)N * 128 * 4);
    float* z1h    = (float*)alloc((size_t)N * 128 * 4);
    float* y2     = (float*)alloc((size_t)N * 64 * 4);
    float* outf   = (float*)d_out;

    hipMemsetAsync(counts, 0, (size_t)N * 4, stream);

    int eb   = (E + 255) / 256;
    int nblk = (N + 2047) / 2048;
    hist_kernel<<<eb, 256, 0, stream>>>(dst, counts, E);
    scan1_kernel<<<nblk, 256, 0, stream>>>(counts, bsums, N);
    scan2_kernel<<<1, 64, 0, stream>>>(bsums, nblk);
    scan3_kernel<<<nblk, 256, 0, stream>>>(counts, bsums, rowp, N, E);
    hipMemcpyAsync(cursor, rowp, (size_t)N * 4, hipMemcpyDeviceToDevice, stream);
    fill_kernel<<<eb, 256, 0, stream>>>(src, dst, cursor, col, E);

    int gb = (N + 63) / 64;
    int ab = (N + 3) / 4;
    // layer 1: y1 = x@Wl1^T ; z1h = x@Wr1^T + bl1
    gemm_dual_kernel<128><<<gb, 256, 0, stream>>>(x, Wl1, Wr1, bl1, y1, z1h, N);
    // h = relu(BN(agg(y1)/deg + z1h)) in-place in z1h
    agg_bn_relu_kernel<<<ab, 256, 0, stream>>>(y1, col, rowp, z1h, bn_g, bn_b, bn_rm, bn_rv, N);
    // layer 2: y2 = h@Wl2^T ; d_out = h@Wr2^T + bl2
    gemm_dual_kernel<64><<<gb, 256, 0, stream>>>(z1h, Wl2, Wr2, bl2, y2, outf, N);
    // d_out += agg(y2)/deg
    agg_out_kernel<<<ab, 256, 0, stream>>>(y2, col, rowp, outf, N);
}